// Round 10
// baseline (46.394 us; speedup 1.0000x reference)
//
#include <hip/hip_runtime.h>

#define NB 8
#define SS 2048
#define DD 128
// 1/sqrt(8) * log2(e): exp(x/sqrt8) = exp2(x*SCALE2)
#define SCALE2 0.5101817664764817f
#define NEGINF -3.0e38f

typedef _Float16 f16x8 __attribute__((ext_vector_type(8)));
typedef float f32x16 __attribute__((ext_vector_type(16)));
typedef unsigned short u16;
typedef u16 u16x8 __attribute__((ext_vector_type(8)));
typedef unsigned int u32;

__device__ __forceinline__ u32 pkrtz(float a, float b) {
    u32 w;
    asm("v_cvt_pkrtz_f16_f32 %0, %1, %2" : "=v"(w) : "v"(a), "v"(b));
    return w;
}

// ---------------- Kernel 1: U = quantum_measure(x, theta) ----------------
// Fragment-order f16 layouts (per batch, per 32-row s-tile t), for 32x32x16 MFMA:
//  G1 : chunk16B[t*512 + kc*64 + hi*32 + r]  holds U[t*32+r][kc*16+hi*8 + 0..7]
//  G2t: chunk16B[t*512 + (dt*2+kc2)*64 + hi*32 + lo5] holds U[t*32+kc2*16+hi*8+u][dt*32+lo5]
__global__ __launch_bounds__(512) void qmeasure_kernel(const float* __restrict__ x,
                                                       const float* __restrict__ theta,
                                                       u16* __restrict__ G1,
                                                       u16* __restrict__ G2) {
    __shared__ u16 olds[32][136];
    const int bid = blockIdx.x;
    const int b = bid & 7;
    const int t = bid >> 3;
    const int tid = threadIdx.x;
    const int s = tid >> 4;
    const int c = tid & 15;

    float th[8];
    *(float4*)th = *(const float4*)theta;
    *(float4*)(th + 4) = *(const float4*)(theta + 4);

    const float* xp = x + (((size_t)b * SS + t * 32 + s) * DD) + c * 8;
    float4 a = *(const float4*)xp;
    float4 a2 = *(const float4*)(xp + 4);
    float cc[8];
    cc[0] = __cosf(a.x + th[0]);  cc[1] = __cosf(a.y + th[1]);
    cc[2] = __cosf(a.z + th[2]);  cc[3] = __cosf(a.w + th[3]);
    cc[4] = __cosf(a2.x + th[4]); cc[5] = __cosf(a2.y + th[5]);
    cc[6] = __cosf(a2.z + th[6]); cc[7] = __cosf(a2.w + th[7]);
    float o[8];
    o[1] = cc[0] * cc[1];
    o[2] = o[1] * cc[2]; o[3] = o[2] * cc[3]; o[4] = o[3] * cc[4];
    o[5] = o[4] * cc[5]; o[6] = o[5] * cc[6]; o[7] = o[6] * cc[7];
    float z = cc[1] * cc[2]; z *= cc[3]; z *= cc[4]; z *= cc[5]; z *= cc[6]; z *= cc[7];
    o[0] = z;

    u16x8 w;
#pragma unroll
    for (int e = 0; e < 8; ++e) w[e] = __builtin_bit_cast(u16, (_Float16)o[e]);
    *(u16x8*)&olds[s][c * 8] = w;
    __syncthreads();

    {
        const int kc = tid >> 6, hh = (tid >> 5) & 1, r = tid & 31;
        u16x8 g;
#pragma unroll
        for (int u = 0; u < 8; ++u) g[u] = olds[r][kc * 16 + hh * 8 + u];
        *(u16x8*)(G1 + (size_t)b * (SS * DD) + ((size_t)t * 512 + tid) * 8) = g;
    }
    {
        const int lo5 = tid & 31;
        const int hh = (tid >> 5) & 1;
        const int dkc = tid >> 6;
        const int dt = dkc >> 1, kc2 = dkc & 1;
        u16x8 g;
#pragma unroll
        for (int u = 0; u < 8; ++u) g[u] = olds[kc2 * 16 + hh * 8 + u][dt * 32 + lo5];
        const int chunk = t * 512 + dkc * 64 + hh * 32 + lo5;
        *(u16x8*)(G2 + (size_t)b * (SS * DD) + (size_t)chunk * 8) = g;
    }
}

// ---------------- Kernel 2: flash attention, TRUE 4 waves/SIMD ----------------
// grid 512 = 8 batches (bid&7, XCD-pinned) x 64 q-subtiles of 32 rows.
// block 512 thr = 8 waves, wave = one kv-EIGHTH (256 kv = 8 iters x 32).
// 2 blocks/CU x 8 waves = 16 waves/CU = 4 waves/SIMD (VGPR capped at 128,
// body proven spill-free at this cap in R8). Direct global->reg frag loads,
// zero LDS/barriers in the main loop. 8-way kq merge via LDS (2 dt-half rounds).
__global__ __launch_bounds__(512, 4) void qattn_kernel(const u16* __restrict__ G1g,
                                                       const u16* __restrict__ G2g,
                                                       float* __restrict__ out) {
    __shared__ float obuf[7][2][16][64];   // 56 KB: partials of waves 1..7, 2 dt per round
    __shared__ float mlb[7][2][32];        // m/l of waves 1..7

    const int tid = threadIdx.x;
    const int lane = tid & 63;
    const int kq = tid >> 6;        // wave = kv eighth 0..7
    const int lo5 = lane & 31;
    const int hi = lane >> 5;
    const int bid = blockIdx.x;
    const int b = bid & 7;
    const int qt = bid >> 3;        // q-subtile 0..63 (32 rows)
    const int lane8 = lane * 8;

    const u16* G1b = G1g + (size_t)b * (SS * DD);
    const u16* G2b = G2g + (size_t)b * (SS * DD);

    // Q fragments (B-operand), persistent (32 VGPR)
    f16x8 qf[8];
    {
        const u16* qp = G1b + (size_t)qt * 4096 + lane8;
#pragma unroll
        for (int kc = 0; kc < 8; ++kc) qf[kc] = *(const f16x8*)(qp + kc * 512);
    }

    f32x16 accT[4];
#pragma unroll
    for (int dt = 0; dt < 4; ++dt)
#pragma unroll
        for (int e = 0; e < 16; ++e) accT[dt][e] = 0.f;
    float m = NEGINF, l = 0.f;

    for (int it = 0; it < 8; ++it) {
        const int t = kq * 8 + it;      // 32-kv tile 0..63
        const u16* kp = G1b + (size_t)t * 4096 + lane8;
        const u16* vp = G2b + (size_t)t * 4096 + lane8;

        // S^T = K . Q^T (frags loaded JIT)
        f32x16 acc;
#pragma unroll
        for (int e = 0; e < 16; ++e) acc[e] = 0.f;
        __builtin_amdgcn_s_setprio(1);
#pragma unroll
        for (int kc = 0; kc < 8; ++kc) {
            f16x8 kf = *(const f16x8*)(kp + kc * 512);
            acc = __builtin_amdgcn_mfma_f32_32x32x16_f16(kf, qf[kc], acc, 0, 0, 0);
        }
        __builtin_amdgcn_s_setprio(0);

        // online softmax (exp2 domain), defer-max THR=8; lane ^32 shares q
        float ma = fmaxf(fmaxf(acc[0], acc[1]), acc[2]);
        float mb = fmaxf(fmaxf(acc[8], acc[9]), acc[10]);
        ma = fmaxf(fmaxf(ma, acc[3]), acc[4]);
        mb = fmaxf(fmaxf(mb, acc[11]), acc[12]);
        ma = fmaxf(fmaxf(ma, acc[5]), acc[6]);
        mb = fmaxf(fmaxf(mb, acc[13]), acc[14]);
        ma = fmaxf(fmaxf(ma, acc[7]), mb);
        float tmax = fmaxf(ma, acc[15]) * SCALE2;
        tmax = fmaxf(tmax, __shfl_xor(tmax, 32));
        if (!__all(tmax <= m + 8.f)) {
            const float mnew = fmaxf(m, tmax);
            const float corr = exp2f(m - mnew);
            l *= corr;
#pragma unroll
            for (int dt = 0; dt < 4; ++dt)
#pragma unroll
                for (int e = 0; e < 16; ++e) accT[dt][e] *= corr;
            m = mnew;
        }
#pragma unroll
        for (int r = 0; r < 16; ++r) acc[r] = exp2f(acc[r] * SCALE2 - m);
        float s0 = (acc[0] + acc[1]) + (acc[2] + acc[3]);
        float s1 = (acc[4] + acc[5]) + (acc[6] + acc[7]);
        float s2 = (acc[8] + acc[9]) + (acc[10] + acc[11]);
        float s3 = (acc[12] + acc[13]) + (acc[14] + acc[15]);
        float rowsum = (s0 + s1) + (s2 + s3);
        rowsum += __shfl_xor(rowsum, 32);
        l += rowsum;

        // P^T B-frags via cvt_pk + permlane32_swap
        f16x8 pa[2];
#pragma unroll
        for (int kc2 = 0; kc2 < 2; ++kc2) {
            const int r0 = kc2 * 8;
            u32 w0 = pkrtz(acc[r0 + 0], acc[r0 + 1]);
            u32 w2 = pkrtz(acc[r0 + 4], acc[r0 + 5]);
            asm("v_permlane32_swap_b32 %0, %1" : "+v"(w0), "+v"(w2));
            u32 w1 = pkrtz(acc[r0 + 2], acc[r0 + 3]);
            u32 w3 = pkrtz(acc[r0 + 6], acc[r0 + 7]);
            asm("v_permlane32_swap_b32 %0, %1" : "+v"(w1), "+v"(w3));
            union { u32 w[4]; f16x8 v; } u;
            u.w[0] = w0; u.w[1] = w1; u.w[2] = w2; u.w[3] = w3;
            pa[kc2] = u.v;
        }

        // O^T += V^T . P^T (V frags JIT)
        __builtin_amdgcn_s_setprio(1);
#pragma unroll
        for (int dt = 0; dt < 4; ++dt) {
            f16x8 vf0 = *(const f16x8*)(vp + (dt * 2 + 0) * 512);
            f16x8 vf1 = *(const f16x8*)(vp + (dt * 2 + 1) * 512);
            f32x16 a = accT[dt];
            a = __builtin_amdgcn_mfma_f32_32x32x16_f16(vf0, pa[0], a, 0, 0, 0);
            a = __builtin_amdgcn_mfma_f32_32x32x16_f16(vf1, pa[1], a, 0, 0, 0);
            accT[dt] = a;
        }
        __builtin_amdgcn_s_setprio(0);
    }

    // ---- 8-way kq merge via LDS (two dt-half rounds) ----
    if (kq > 0) {
        if (hi == 0) {
            mlb[kq - 1][0][lo5] = m;
            mlb[kq - 1][1][lo5] = l;
        }
#pragma unroll
        for (int dh = 0; dh < 2; ++dh)
#pragma unroll
            for (int r = 0; r < 16; ++r)
                obuf[kq - 1][dh][r][lane] = accT[dh][r];
    }
    __syncthreads();
    float wgt[8], linv;
    if (kq == 0) {
        float mm[8], ll[8];
        mm[0] = m; ll[0] = l;
#pragma unroll
        for (int j = 1; j < 8; ++j) {
            mm[j] = mlb[j - 1][0][lo5];
            ll[j] = mlb[j - 1][1][lo5];
        }
        float ms = fmaxf(fmaxf(fmaxf(mm[0], mm[1]), fmaxf(mm[2], mm[3])),
                         fmaxf(fmaxf(mm[4], mm[5]), fmaxf(mm[6], mm[7])));
        float den = 0.f;
#pragma unroll
        for (int j = 0; j < 8; ++j) {
            wgt[j] = exp2f(mm[j] - ms);
            den += ll[j] * wgt[j];
        }
        linv = 1.f / den;
        float* orow = out + ((size_t)b * SS + qt * 32 + lo5) * DD;
#pragma unroll
        for (int dt = 0; dt < 2; ++dt)
#pragma unroll
            for (int r = 0; r < 16; ++r) {
                float o = accT[dt][r] * wgt[0];
#pragma unroll
                for (int j = 1; j < 8; ++j) o += obuf[j - 1][dt][r][lane] * wgt[j];
                const int drow = (r & 3) + 8 * (r >> 2) + 4 * hi;
                orow[dt * 32 + drow] = o * linv;
            }
    }
    __syncthreads();
    if (kq > 0) {
#pragma unroll
        for (int dh = 0; dh < 2; ++dh)
#pragma unroll
            for (int r = 0; r < 16; ++r)
                obuf[kq - 1][dh][r][lane] = accT[2 + dh][r];
    }
    __syncthreads();
    if (kq == 0) {
        float* orow = out + ((size_t)b * SS + qt * 32 + lo5) * DD;
#pragma unroll
        for (int dh = 0; dh < 2; ++dh) {
            const int dt = 2 + dh;
#pragma unroll
            for (int r = 0; r < 16; ++r) {
                float o = accT[dt][r] * wgt[0];
#pragma unroll
                for (int j = 1; j < 8; ++j) o += obuf[j - 1][dh][r][lane] * wgt[j];
                const int drow = (r & 3) + 8 * (r >> 2) + 4 * hi;
                orow[dt * 32 + drow] = o * linv;
            }
        }
    }
}

extern "C" void kernel_launch(void* const* d_in, const int* in_sizes, int n_in,
                              void* d_out, int out_size, void* d_ws, size_t ws_size,
                              hipStream_t stream) {
    const float* x = (const float*)d_in[0];
    const float* theta = (const float*)d_in[1];
    float* outp = (float*)d_out;
    u16* G1 = (u16*)d_ws;                       // 4 MB
    u16* G2 = G1 + (size_t)NB * SS * DD;        // +4 MB

    qmeasure_kernel<<<512, 512, 0, stream>>>(x, theta, G1, G2);
    qattn_kernel<<<512, 512, 0, stream>>>(G1, G2, outp);
}